// Round 1
// baseline (840.834 us; speedup 1.0000x reference)
//
#include <hip/hip_runtime.h>
#include <stdint.h>

typedef __attribute__((ext_vector_type(8))) __bf16 bf16x8;
typedef __attribute__((ext_vector_type(4))) float f32x4;

#define DEVI __device__ __forceinline__

// ---------- bf16 helpers (manual RNE, no API surprises) ----------
DEVI unsigned short f2bf(float f) {
  unsigned u = __builtin_bit_cast(unsigned, f);
  u += 0x7fffu + ((u >> 16) & 1u);
  return (unsigned short)(u >> 16);
}
DEVI float bf2f(unsigned short h) {
  unsigned u = ((unsigned)h) << 16;
  return __builtin_bit_cast(float, u);
}

DEVI void gload_lds16(const unsigned short* g, unsigned char* lds) {
  __builtin_amdgcn_global_load_lds(
      (const __attribute__((address_space(1))) void*)g,
      (__attribute__((address_space(3))) void*)lds, 16, 0, 0);
}

// ---------- elementwise: fp32 -> bf16 hi/lo split ----------
__global__ __launch_bounds__(256) void split_kernel(
    const float* __restrict__ x, unsigned short* __restrict__ hi,
    unsigned short* __restrict__ lo, int nvec) {
  long long i = (long long)blockIdx.x * 256 + threadIdx.x;
  if (i >= nvec) return;
  float4 f = reinterpret_cast<const float4*>(x)[i];
  ushort4 h, l;
  h.x = f2bf(f.x); l.x = f2bf(f.x - bf2f(h.x));
  h.y = f2bf(f.y); l.y = f2bf(f.y - bf2f(h.y));
  h.z = f2bf(f.z); l.z = f2bf(f.z - bf2f(h.z));
  h.w = f2bf(f.w); l.w = f2bf(f.w - bf2f(h.w));
  reinterpret_cast<ushort4*>(hi)[i] = h;
  reinterpret_cast<ushort4*>(lo)[i] = l;
}

__global__ __launch_bounds__(256) void cast_kernel(
    const float* __restrict__ x, unsigned short* __restrict__ hi, int nvec) {
  long long i = (long long)blockIdx.x * 256 + threadIdx.x;
  if (i >= nvec) return;
  float4 f = reinterpret_cast<const float4*>(x)[i];
  ushort4 h;
  h.x = f2bf(f.x); h.y = f2bf(f.y); h.z = f2bf(f.z); h.w = f2bf(f.w);
  reinterpret_cast<ushort4*>(hi)[i] = h;
}

// ---------- v [B][S][D] fp32 -> vT [B][D][S] bf16 ----------
__global__ __launch_bounds__(256) void transpose_cast_kernel(
    const float* __restrict__ v, unsigned short* __restrict__ vT, int S, int D) {
  __shared__ float tile[32][33];
  const int tx = threadIdx.x, ty = threadIdx.y;
  const int k0 = blockIdx.x * 32, d0 = blockIdx.y * 32, b = blockIdx.z;
  const float* vb = v + (long long)b * S * D;
  unsigned short* vTb = vT + (long long)b * S * D;
#pragma unroll
  for (int j = 0; j < 4; ++j) {
    int kl = ty + j * 8;
    tile[kl][tx] = vb[(long long)(k0 + kl) * D + d0 + tx];
  }
  __syncthreads();
#pragma unroll
  for (int j = 0; j < 4; ++j) {
    int dl = ty + j * 8;
    vTb[(long long)(d0 + dl) * S + k0 + tx] = f2bf(tile[tx][dl]);
  }
}

// ---------- masked row softmax: scores fp32 -> p bf16 ----------
DEVI float wred_max(float x) {
#pragma unroll
  for (int o = 32; o > 0; o >>= 1) x = fmaxf(x, __shfl_xor(x, o));
  return x;
}
DEVI float wred_sum(float x) {
#pragma unroll
  for (int o = 32; o > 0; o >>= 1) x += __shfl_xor(x, o);
  return x;
}

__global__ __launch_bounds__(256) void softmax_kernel(
    const float* __restrict__ scores, const float* __restrict__ cell,
    const float* __restrict__ seq, unsigned short* __restrict__ p, int S) {
  const long long row = blockIdx.x;          // (b, q) flattened, S rows per batch
  const int b = (int)(row / S);
  const long long base = row * S;
  const int t = threadIdx.x, lane = t & 63, wid = t >> 6;
  __shared__ float red[8];

  const float4* sc = (const float4*)(scores + base);
  const float4* cm = (const float4*)(cell + base);
  const float4* sm = (const float4*)(seq + (long long)b * S);

  float4 x0 = sc[2 * t], x1 = sc[2 * t + 1];
  float4 c0 = cm[2 * t], c1 = cm[2 * t + 1];
  float4 q0 = sm[2 * t], q1 = sm[2 * t + 1];
  float v[8];
  v[0] = x0.x + __logf(c0.x) + __logf(q0.x);
  v[1] = x0.y + __logf(c0.y) + __logf(q0.y);
  v[2] = x0.z + __logf(c0.z) + __logf(q0.z);
  v[3] = x0.w + __logf(c0.w) + __logf(q0.w);
  v[4] = x1.x + __logf(c1.x) + __logf(q1.x);
  v[5] = x1.y + __logf(c1.y) + __logf(q1.y);
  v[6] = x1.z + __logf(c1.z) + __logf(q1.z);
  v[7] = x1.w + __logf(c1.w) + __logf(q1.w);

  float m = v[0];
#pragma unroll
  for (int j = 1; j < 8; ++j) m = fmaxf(m, v[j]);
  m = wred_max(m);
  if (lane == 0) red[wid] = m;
  __syncthreads();
  m = fmaxf(fmaxf(red[0], red[1]), fmaxf(red[2], red[3]));

  float e[8], s = 0.f;
#pragma unroll
  for (int j = 0; j < 8; ++j) { e[j] = __expf(v[j] - m); s += e[j]; }
  s = wred_sum(s);
  if (lane == 0) red[4 + wid] = s;
  __syncthreads();
  s = red[4] + red[5] + red[6] + red[7];
  const float inv = 1.0f / s;

  uint4 o;
  o.x = (unsigned)f2bf(e[0] * inv) | ((unsigned)f2bf(e[1] * inv) << 16);
  o.y = (unsigned)f2bf(e[2] * inv) | ((unsigned)f2bf(e[3] * inv) << 16);
  o.z = (unsigned)f2bf(e[4] * inv) | ((unsigned)f2bf(e[5] * inv) << 16);
  o.w = (unsigned)f2bf(e[6] * inv) | ((unsigned)f2bf(e[7] * inv) << 16);
  ((uint4*)(p + base))[t] = o;
}

// ---------- C = A * B^T  (both operands row-major [rows][K]) ----------
// SPLIT==3: A = Ah+Al, B = Bh+Bl, C = AhBh + AhBl + AlBh  (fp32-grade)
// OUTMODE: 0 = fp32 (Cf), 1 = bf16 (Chi), 2 = bf16 hi/lo split (Chi,Clo)
template <int SPLIT, int OUTMODE, bool BIAS>
__global__ __launch_bounds__(256, 2) void gemm_bt(
    const unsigned short* __restrict__ Ah, const unsigned short* __restrict__ Al,
    const unsigned short* __restrict__ Bh, const unsigned short* __restrict__ Bl,
    float* __restrict__ Cf, unsigned short* __restrict__ Chi,
    unsigned short* __restrict__ Clo, const float* __restrict__ bias,
    int M, int N, int K, long long sA, long long sB, long long sC) {
  constexpr int BK = (SPLIT == 3) ? 32 : 64;
  constexpr int TILEB = 128 * BK * 2;  // bytes per LDS tile
  constexpr int NT = (SPLIT == 3) ? 4 : 2;
  __shared__ __align__(16) unsigned char smem[2 * NT * TILEB];  // 64 KiB

  const int tid = threadIdx.x, lane = tid & 63, wid = tid >> 6;
  const int wm = wid >> 1, wn = wid & 1;
  const int r16 = lane & 15, q4 = lane >> 4;
  const int bn0 = blockIdx.x * 128, bm0 = blockIdx.y * 128;
  const int bz = blockIdx.z;

  Ah += (long long)bz * sA;
  Bh += (long long)bz * sB;
  if (SPLIT == 3) { Al += (long long)bz * sA; Bl += (long long)bz * sB; }
  const long long cb = (long long)bz * sC;

  // stage one K-step of tiles; source global addresses pre-swizzled so that
  // linear global_load_lds writes land XOR-swizzled (rule #21)
  auto stage = [&](int buf, int kt) {
    const int k0 = kt * BK;
    if (SPLIT == 3) {
      const unsigned short* src = (wid == 0) ? Ah : (wid == 1) ? Al : (wid == 2) ? Bh : Bl;
      const int row0 = (wid < 2) ? bm0 : bn0;
      unsigned char* dst = smem + (size_t)(buf * 4 + wid) * TILEB;
#pragma unroll
      for (int i = 0; i < 8; ++i) {
        const int row = i * 16 + (lane >> 2);
        const int sg = (lane & 3) ^ ((row >> 1) & 3);
        gload_lds16(src + (long long)(row0 + row) * K + k0 + sg * 8, dst + i * 1024);
      }
    } else {
      const unsigned short* src = (wid < 2) ? Ah : Bh;
      const int row0 = (wid < 2) ? bm0 : bn0;
      const int half = wid & 1;
      unsigned char* dst = smem + (size_t)(buf * 2 + (wid >> 1)) * TILEB + half * 8192;
#pragma unroll
      for (int i = 0; i < 8; ++i) {
        const int row = half * 64 + i * 8 + (lane >> 3);
        const int sg = (lane & 7) ^ (row & 7);
        gload_lds16(src + (long long)(row0 + row) * K + k0 + sg * 8, dst + i * 1024);
      }
    }
  };

  auto foff = [&](int r, int ks) -> int {   // swizzled frag byte offset in tile
    return (BK == 64) ? (r * 128 + ((((ks << 2) + q4) ^ (r & 7)) << 4))
                      : (r * 64 + ((q4 ^ ((r >> 1) & 3)) << 4));
  };

  f32x4 acc[4][4];
#pragma unroll
  for (int mi = 0; mi < 4; ++mi)
#pragma unroll
    for (int ni = 0; ni < 4; ++ni) acc[mi][ni] = (f32x4){0.f, 0.f, 0.f, 0.f};

  const int nk = K / BK;
  int buf = 0;
  stage(0, 0);
  for (int kt = 0; kt < nk; ++kt) {
    __syncthreads();  // drains vmcnt: staged tiles ready; prev reads done
    if (kt + 1 < nk) stage(buf ^ 1, kt + 1);
    const unsigned char* tA = smem + (size_t)((SPLIT == 3) ? (buf * 4 + 0) : (buf * 2 + 0)) * TILEB;
    const unsigned char* tB = smem + (size_t)((SPLIT == 3) ? (buf * 4 + 2) : (buf * 2 + 1)) * TILEB;
    const unsigned char* tAl = (SPLIT == 3) ? smem + (size_t)(buf * 4 + 1) * TILEB : nullptr;
    const unsigned char* tBl = (SPLIT == 3) ? smem + (size_t)(buf * 4 + 3) * TILEB : nullptr;
#pragma unroll
    for (int ks = 0; ks < BK / 32; ++ks) {
      bf16x8 a_h[4], b_h[4], a_l[4], b_l[4];
#pragma unroll
      for (int mi = 0; mi < 4; ++mi) {
        const int r = wm * 64 + mi * 16 + r16;
        const int off = foff(r, ks);
        a_h[mi] = *(const bf16x8*)(tA + off);
        if (SPLIT == 3) a_l[mi] = *(const bf16x8*)(tAl + off);
      }
#pragma unroll
      for (int ni = 0; ni < 4; ++ni) {
        const int r = wn * 64 + ni * 16 + r16;
        const int off = foff(r, ks);
        b_h[ni] = *(const bf16x8*)(tB + off);
        if (SPLIT == 3) b_l[ni] = *(const bf16x8*)(tBl + off);
      }
#pragma unroll
      for (int mi = 0; mi < 4; ++mi)
#pragma unroll
        for (int ni = 0; ni < 4; ++ni) {
          acc[mi][ni] = __builtin_amdgcn_mfma_f32_16x16x32_bf16(a_h[mi], b_h[ni], acc[mi][ni], 0, 0, 0);
          if (SPLIT == 3) {
            acc[mi][ni] = __builtin_amdgcn_mfma_f32_16x16x32_bf16(a_h[mi], b_l[ni], acc[mi][ni], 0, 0, 0);
            acc[mi][ni] = __builtin_amdgcn_mfma_f32_16x16x32_bf16(a_l[mi], b_h[ni], acc[mi][ni], 0, 0, 0);
          }
        }
    }
    buf ^= 1;
  }

  // epilogue: C/D layout col = lane&15, row = (lane>>4)*4 + reg  [m89/m91]
#pragma unroll
  for (int mi = 0; mi < 4; ++mi) {
#pragma unroll
    for (int ni = 0; ni < 4; ++ni) {
      const int col = bn0 + wn * 64 + ni * 16 + r16;
      const float bv = BIAS ? bias[col] : 0.0f;
#pragma unroll
      for (int j = 0; j < 4; ++j) {
        const int row = bm0 + wm * 64 + mi * 16 + q4 * 4 + j;
        const float cv = acc[mi][ni][j] + bv;
        const long long idx = cb + (long long)row * N + col;
        if (OUTMODE == 0) {
          Cf[idx] = cv;
        } else if (OUTMODE == 1) {
          Chi[idx] = f2bf(cv);
        } else {
          unsigned short h = f2bf(cv);
          Chi[idx] = h;
          Clo[idx] = f2bf(cv - bf2f(h));
        }
      }
    }
  }
}

// ---------- host ----------
extern "C" void kernel_launch(void* const* d_in, const int* in_sizes, int n_in,
                              void* d_out, int out_size, void* d_ws, size_t ws_size,
                              hipStream_t stream) {
  const float* query = (const float*)d_in[0];
  const float* key   = (const float*)d_in[1];
  const float* value = (const float*)d_in[2];
  const float* cell  = (const float*)d_in[3];
  const float* seq   = (const float*)d_in[4];
  const float* W_k   = (const float*)d_in[5];
  const float* b_k   = (const float*)d_in[6];
  const float* W_o   = (const float*)d_in[7];
  const float* b_o   = (const float*)d_in[8];
  float* out = (float*)d_out;

  const int B = 8, S = 2048, D = 1024;
  const long long NE = (long long)B * S * D;  // 16,777,216
  const long long NS = (long long)B * S * S;  // 33,554,432

  unsigned char* ws = (unsigned char*)d_ws;
  size_t off = 0;
  auto alloc = [&](size_t bytes) -> unsigned char* {
    unsigned char* pp = ws + off;
    off += (bytes + 255) & ~(size_t)255;
    return pp;
  };
  unsigned short* qhi  = (unsigned short*)alloc(NE * 2);
  unsigned short* qlo  = (unsigned short*)alloc(NE * 2);
  unsigned short* kphi = (unsigned short*)alloc(NE * 2);
  unsigned short* kplo = (unsigned short*)alloc(NE * 2);
  unsigned short* vT   = (unsigned short*)alloc(NE * 2);
  unsigned short* khi  = (unsigned short*)alloc(NE * 2);  // becomes p after k_proj
  unsigned short* klo  = (unsigned short*)alloc(NE * 2);  // (contiguous with khi)
  float*          scores = (float*)alloc(NS * 4);         // becomes xbf after softmax
  unsigned short* wkhi = (unsigned short*)alloc((size_t)D * D * 2);
  unsigned short* wklo = (unsigned short*)alloc((size_t)D * D * 2);
  unsigned short* wo   = (unsigned short*)alloc((size_t)D * D * 2);
  unsigned short* p    = khi;                   // 64 MiB alias over khi+klo
  unsigned short* xbf  = (unsigned short*)scores;  // 32 MiB alias over scores
  (void)ws_size; (void)in_sizes; (void)n_in; (void)out_size;

  // 1. hi/lo splits + casts
  split_kernel<<<dim3(NE / 1024), 256, 0, stream>>>(query, qhi, qlo, (int)(NE / 4));
  split_kernel<<<dim3(NE / 1024), 256, 0, stream>>>(key, khi, klo, (int)(NE / 4));
  split_kernel<<<dim3(D * D / 1024), 256, 0, stream>>>(W_k, wkhi, wklo, D * D / 4);
  cast_kernel<<<dim3(D * D / 1024), 256, 0, stream>>>(W_o, wo, D * D / 4);
  transpose_cast_kernel<<<dim3(S / 32, D / 32, B), dim3(32, 8), 0, stream>>>(value, vT, S, D);

  // 2. k_proj = key @ W_k^T + b_k  (split precision, split output)
  gemm_bt<3, 2, true><<<dim3(D / 128, (B * S) / 128, 1), 256, 0, stream>>>(
      khi, klo, wkhi, wklo, nullptr, kphi, kplo, b_k, B * S, D, D, 0, 0, 0);

  // 3. scores = q @ k_proj^T  (batched, split precision, fp32 out)
  gemm_bt<3, 0, false><<<dim3(S / 128, S / 128, B), 256, 0, stream>>>(
      qhi, qlo, kphi, kplo, scores, nullptr, nullptr, nullptr, S, S, D,
      (long long)S * D, (long long)S * D, (long long)S * S);

  // 4. masked softmax -> p (bf16), overwrites khi/klo region
  softmax_kernel<<<dim3(B * S), 256, 0, stream>>>(scores, cell, seq, p, S);

  // 5. x = p @ vT^T  (batched, bf16 out), overwrites scores region
  gemm_bt<1, 1, false><<<dim3(D / 128, S / 128, B), 256, 0, stream>>>(
      p, nullptr, vT, nullptr, nullptr, xbf, nullptr, nullptr, S, D, S,
      (long long)S * S, (long long)S * D, (long long)S * D);

  // 6. out = x @ W_o^T + b_o  (fp32 out)
  gemm_bt<1, 0, true><<<dim3(D / 128, (B * S) / 128, 1), 256, 0, stream>>>(
      xbf, nullptr, wo, nullptr, out, nullptr, nullptr, b_o, B * S, D, D, 0, 0, 0);
}

// Round 2
// 811.913 us; speedup vs baseline: 1.0356x; 1.0356x over previous
//
#include <hip/hip_runtime.h>
#include <stdint.h>

typedef __attribute__((ext_vector_type(8))) __bf16 bf16x8;
typedef __attribute__((ext_vector_type(4))) float f32x4;

#define DEVI __device__ __forceinline__

// ---------- bf16 helpers (manual RNE) ----------
DEVI unsigned short f2bf(float f) {
  unsigned u = __builtin_bit_cast(unsigned, f);
  u += 0x7fffu + ((u >> 16) & 1u);
  return (unsigned short)(u >> 16);
}
DEVI float bf2f(unsigned short h) {
  unsigned u = ((unsigned)h) << 16;
  return __builtin_bit_cast(float, u);
}

DEVI void gload_lds16(const unsigned short* g, unsigned char* lds) {
  __builtin_amdgcn_global_load_lds(
      (const __attribute__((address_space(1))) void*)g,
      (__attribute__((address_space(3))) void*)lds, 16, 0, 0);
}

#define MEMFENCE asm volatile("" ::: "memory")
#define BARRIER()                      \
  do {                                 \
    MEMFENCE;                          \
    __builtin_amdgcn_s_barrier();      \
    MEMFENCE;                          \
  } while (0)

// ---------- elementwise: fp32 -> bf16 hi/lo split ----------
__global__ __launch_bounds__(256) void split_kernel(
    const float* __restrict__ x, unsigned short* __restrict__ hi,
    unsigned short* __restrict__ lo, int nvec) {
  long long i = (long long)blockIdx.x * 256 + threadIdx.x;
  if (i >= nvec) return;
  float4 f = reinterpret_cast<const float4*>(x)[i];
  ushort4 h, l;
  h.x = f2bf(f.x); l.x = f2bf(f.x - bf2f(h.x));
  h.y = f2bf(f.y); l.y = f2bf(f.y - bf2f(h.y));
  h.z = f2bf(f.z); l.z = f2bf(f.z - bf2f(h.z));
  h.w = f2bf(f.w); l.w = f2bf(f.w - bf2f(h.w));
  reinterpret_cast<ushort4*>(hi)[i] = h;
  reinterpret_cast<ushort4*>(lo)[i] = l;
}

__global__ __launch_bounds__(256) void cast_kernel(
    const float* __restrict__ x, unsigned short* __restrict__ hi, int nvec) {
  long long i = (long long)blockIdx.x * 256 + threadIdx.x;
  if (i >= nvec) return;
  float4 f = reinterpret_cast<const float4*>(x)[i];
  ushort4 h;
  h.x = f2bf(f.x); h.y = f2bf(f.y); h.z = f2bf(f.z); h.w = f2bf(f.w);
  reinterpret_cast<ushort4*>(hi)[i] = h;
}

// ---------- v [B][S][D] fp32 -> vT [B][D][S] bf16 ----------
__global__ __launch_bounds__(256) void transpose_cast_kernel(
    const float* __restrict__ v, unsigned short* __restrict__ vT, int S, int D) {
  __shared__ float tile[32][33];
  const int tx = threadIdx.x, ty = threadIdx.y;
  const int k0 = blockIdx.x * 32, d0 = blockIdx.y * 32, b = blockIdx.z;
  const float* vb = v + (long long)b * S * D;
  unsigned short* vTb = vT + (long long)b * S * D;
#pragma unroll
  for (int j = 0; j < 4; ++j) {
    int kl = ty + j * 8;
    tile[kl][tx] = vb[(long long)(k0 + kl) * D + d0 + tx];
  }
  __syncthreads();
#pragma unroll
  for (int j = 0; j < 4; ++j) {
    int dl = ty + j * 8;
    vTb[(long long)(d0 + dl) * S + k0 + tx] = f2bf(tile[tx][dl]);
  }
}

// ---------- masked row softmax: scores fp32 -> p bf16 ----------
DEVI float wred_max(float x) {
#pragma unroll
  for (int o = 32; o > 0; o >>= 1) x = fmaxf(x, __shfl_xor(x, o));
  return x;
}
DEVI float wred_sum(float x) {
#pragma unroll
  for (int o = 32; o > 0; o >>= 1) x += __shfl_xor(x, o);
  return x;
}

__global__ __launch_bounds__(256) void softmax_kernel(
    const float* __restrict__ scores, const float* __restrict__ cell,
    const float* __restrict__ seq, unsigned short* __restrict__ p, int S) {
  const long long row = blockIdx.x;
  const int b = (int)(row / S);
  const long long base = row * S;
  const int t = threadIdx.x, lane = t & 63, wid = t >> 6;
  __shared__ float red[8];

  const float4* sc = (const float4*)(scores + base);
  const float4* cm = (const float4*)(cell + base);
  const float4* sm = (const float4*)(seq + (long long)b * S);

  float4 x0 = sc[2 * t], x1 = sc[2 * t + 1];
  float4 c0 = cm[2 * t], c1 = cm[2 * t + 1];
  float4 q0 = sm[2 * t], q1 = sm[2 * t + 1];
  float v[8];
  v[0] = x0.x + __logf(c0.x) + __logf(q0.x);
  v[1] = x0.y + __logf(c0.y) + __logf(q0.y);
  v[2] = x0.z + __logf(c0.z) + __logf(q0.z);
  v[3] = x0.w + __logf(c0.w) + __logf(q0.w);
  v[4] = x1.x + __logf(c1.x) + __logf(q1.x);
  v[5] = x1.y + __logf(c1.y) + __logf(q1.y);
  v[6] = x1.z + __logf(c1.z) + __logf(q1.z);
  v[7] = x1.w + __logf(c1.w) + __logf(q1.w);

  float m = v[0];
#pragma unroll
  for (int j = 1; j < 8; ++j) m = fmaxf(m, v[j]);
  m = wred_max(m);
  if (lane == 0) red[wid] = m;
  __syncthreads();
  m = fmaxf(fmaxf(red[0], red[1]), fmaxf(red[2], red[3]));

  float e[8], s = 0.f;
#pragma unroll
  for (int j = 0; j < 8; ++j) { e[j] = __expf(v[j] - m); s += e[j]; }
  s = wred_sum(s);
  if (lane == 0) red[4 + wid] = s;
  __syncthreads();
  s = red[4] + red[5] + red[6] + red[7];
  const float inv = 1.0f / s;

  uint4 o;
  o.x = (unsigned)f2bf(e[0] * inv) | ((unsigned)f2bf(e[1] * inv) << 16);
  o.y = (unsigned)f2bf(e[2] * inv) | ((unsigned)f2bf(e[3] * inv) << 16);
  o.z = (unsigned)f2bf(e[4] * inv) | ((unsigned)f2bf(e[5] * inv) << 16);
  o.w = (unsigned)f2bf(e[6] * inv) | ((unsigned)f2bf(e[7] * inv) << 16);
  ((uint4*)(p + base))[t] = o;
}

// =====================================================================
// 256x256 8-phase GEMM (T3+T4+T5+T2), C = A * B^T, operands row-major [rows][K]
// SPLIT==3: BK=32, granules {Ah,Al,Bh,Bl} (16KB each); C = AhBh+AhBl+AlBh
// SPLIT==1: BK=64, granules {A-half0,A-half1,B-half0,B-half1}
// 8 waves (2M x 4N), per-wave 128x64 output. LDS = 2 slots x 64KB (dynamic).
// Granule #h issues at phase h-5; vmcnt(2) boundary wait once per K-tile.
// =====================================================================
template <int SPLIT, int OUTMODE, bool BIAS>
__global__ __launch_bounds__(512, 2) void gemm256(
    const unsigned short* __restrict__ Ah, const unsigned short* __restrict__ Al,
    const unsigned short* __restrict__ Bh, const unsigned short* __restrict__ Bl,
    float* __restrict__ Cf, unsigned short* __restrict__ Chi,
    unsigned short* __restrict__ Clo, const float* __restrict__ bias,
    int M, int N, int K, long long sA, long long sB, long long sC) {
  constexpr int BK = (SPLIT == 3) ? 32 : 64;
  extern __shared__ unsigned char smem[];  // 131072 bytes

  const int tid = threadIdx.x, lane = tid & 63, wid = tid >> 6;
  const int wm = wid >> 2, wn = wid & 3;       // 2 x 4 waves
  const int r16 = lane & 15, q4 = lane >> 4;
  const int bn0 = blockIdx.x * 256, bm0 = blockIdx.y * 256;
  const int bz = blockIdx.z;

  Ah += (long long)bz * sA;
  Bh += (long long)bz * sB;
  if (SPLIT == 3) { Al += (long long)bz * sA; Bl += (long long)bz * sB; }
  const long long cbase = (long long)bz * sC;
  const int nk = K / BK;

  // stage granule h: tile ts = h>>2, operand j = h&3; LDS dest linear
  // (wave-uniform base), global source pre-swizzled (rule #21).
  auto stageg = [&](int h) {
    const int ts = h >> 2, j = h & 3;
    const int k0 = ts * BK;
    unsigned char* slotb = smem + (ts & 1) * 65536;
    if constexpr (SPLIT == 3) {
      const unsigned short* src = (j == 0) ? Ah : (j == 1) ? Al : (j == 2) ? Bh : Bl;
      const int row0 = (j < 2) ? bm0 : bn0;
#pragma unroll
      for (int i = 0; i < 2; ++i) {
        const int seg = i * 8 + wid;              // 0..15
        const int row = seg * 16 + (lane >> 2);   // 0..255
        const int c = (lane & 3) ^ ((row >> 1) & 3);
        gload_lds16(src + (long long)(row0 + row) * K + k0 + c * 8,
                    slotb + j * 16384 + seg * 1024);
      }
    } else {
      const unsigned short* src = (j < 2) ? Ah : Bh;
      const int row0 = (j < 2) ? bm0 : bn0;
#pragma unroll
      for (int i = 0; i < 2; ++i) {
        const int seg = i * 8 + wid;
        const int row = (j & 1) * 128 + seg * 8 + (lane >> 3);
        const int c = (lane & 7) ^ (row & 7);
        gload_lds16(src + (long long)(row0 + row) * K + k0 + c * 8,
                    slotb + (j >> 1) * 32768 + (j & 1) * 16384 + seg * 1024);
      }
    }
  };

  f32x4 acc[8][4];
#pragma unroll
  for (int mi = 0; mi < 8; ++mi)
#pragma unroll
    for (int ni = 0; ni < 4; ++ni) acc[mi][ni] = (f32x4){0.f, 0.f, 0.f, 0.f};

  bf16x8 a_h[4], a_l[4], b_h[2], b_l[2];  // "l" = low-part (SPLIT3) or ks=1 (SPLIT1)

  // prologue: granules 0..4; need 0..3 landed (tile 0), granule 4 may fly.
  stageg(0); stageg(1); stageg(2); stageg(3); stageg(4);
  asm volatile("s_waitcnt vmcnt(2)" ::: "memory");
  BARRIER();

  for (int tau = 0; tau < nk; ++tau) {
    const unsigned char* sb = smem + (tau & 1) * 65536;
    const int hb = 4 * tau + 5;

    auto LOADA = [&](int rb) {
#pragma unroll
      for (int mq = 0; mq < 4; ++mq) {
        const int r = wm * 128 + rb * 64 + mq * 16 + r16;
        if constexpr (SPLIT == 3) {
          const int o = r * 64 + ((q4 ^ ((r >> 1) & 3)) << 4);
          a_h[mq] = *(const bf16x8*)(sb + o);
          a_l[mq] = *(const bf16x8*)(sb + 16384 + o);
        } else {
          a_h[mq] = *(const bf16x8*)(sb + r * 128 + ((q4 ^ (r & 7)) << 4));
          a_l[mq] = *(const bf16x8*)(sb + r * 128 + (((4 + q4) ^ (r & 7)) << 4));
        }
      }
    };
    auto LOADB = [&](int cb) {
#pragma unroll
      for (int nq = 0; nq < 2; ++nq) {
        const int r = wn * 64 + cb * 32 + nq * 16 + r16;
        if constexpr (SPLIT == 3) {
          const int o = r * 64 + ((q4 ^ ((r >> 1) & 3)) << 4);
          b_h[nq] = *(const bf16x8*)(sb + 32768 + o);
          b_l[nq] = *(const bf16x8*)(sb + 49152 + o);
        } else {
          b_h[nq] = *(const bf16x8*)(sb + 32768 + r * 128 + ((q4 ^ (r & 7)) << 4));
          b_l[nq] = *(const bf16x8*)(sb + 32768 + r * 128 + (((4 + q4) ^ (r & 7)) << 4));
        }
      }
    };
    auto MMA = [&](int rb, int cb) {
#pragma unroll
      for (int mq = 0; mq < 4; ++mq)
#pragma unroll
        for (int nq = 0; nq < 2; ++nq) {
          f32x4& A = acc[rb * 4 + mq][cb * 2 + nq];
          A = __builtin_amdgcn_mfma_f32_16x16x32_bf16(a_h[mq], b_h[nq], A, 0, 0, 0);
          if constexpr (SPLIT == 3) {
            A = __builtin_amdgcn_mfma_f32_16x16x32_bf16(a_h[mq], b_l[nq], A, 0, 0, 0);
            A = __builtin_amdgcn_mfma_f32_16x16x32_bf16(a_l[mq], b_h[nq], A, 0, 0, 0);
          } else {
            A = __builtin_amdgcn_mfma_f32_16x16x32_bf16(a_l[mq], b_l[nq], A, 0, 0, 0);
          }
        }
    };

#define PHASE_MID(RB, CB)                      \
  BARRIER();                                   \
  asm volatile("s_waitcnt lgkmcnt(0)" ::: "memory"); \
  __builtin_amdgcn_sched_barrier(0);           \
  __builtin_amdgcn_s_setprio(1);               \
  MMA(RB, CB);                                 \
  __builtin_amdgcn_s_setprio(0);               \
  __builtin_amdgcn_sched_barrier(0);           \
  BARRIER()

    // p0: quadrant (0,0)
    LOADA(0); LOADB(0);
    if (hb + 0 < 4 * nk) stageg(hb + 0);
    PHASE_MID(0, 0);
    // p1: (0,1) — reuse A, new B
    LOADB(1);
    if (hb + 1 < 4 * nk) stageg(hb + 1);
    PHASE_MID(0, 1);
    // p2: (1,1) — new A, reuse B
    LOADA(1);
    if (hb + 2 < 4 * nk) stageg(hb + 2);
    PHASE_MID(1, 1);
    // p3: (1,0) — reuse A, new B; K-tile boundary vmcnt
    LOADB(0);
    if (hb + 3 < 4 * nk) {
      stageg(hb + 3);
      asm volatile("s_waitcnt vmcnt(2)" ::: "memory");
    } else {
      asm volatile("s_waitcnt vmcnt(0)" ::: "memory");
    }
    PHASE_MID(1, 0);
#undef PHASE_MID
  }

  // epilogue: C/D layout col = lane&15, row = (lane>>4)*4 + reg  [m89/m91]
#pragma unroll
  for (int mi = 0; mi < 8; ++mi) {
#pragma unroll
    for (int ni = 0; ni < 4; ++ni) {
      const int col = bn0 + wn * 64 + ni * 16 + r16;
      const float bv = BIAS ? bias[col] : 0.0f;
#pragma unroll
      for (int j = 0; j < 4; ++j) {
        const int row = bm0 + wm * 128 + mi * 16 + q4 * 4 + j;
        const float cv = acc[mi][ni][j] + bv;
        const long long idx = cbase + (long long)row * N + col;
        if (OUTMODE == 0) {
          Cf[idx] = cv;
        } else if (OUTMODE == 1) {
          Chi[idx] = f2bf(cv);
        } else {
          unsigned short h = f2bf(cv);
          Chi[idx] = h;
          Clo[idx] = f2bf(cv - bf2f(h));
        }
      }
    }
  }
}

// ---------- proven 128x128 kernel (kept for PV and out-proj) ----------
template <int SPLIT, int OUTMODE, bool BIAS>
__global__ __launch_bounds__(256, 2) void gemm_bt(
    const unsigned short* __restrict__ Ah, const unsigned short* __restrict__ Al,
    const unsigned short* __restrict__ Bh, const unsigned short* __restrict__ Bl,
    float* __restrict__ Cf, unsigned short* __restrict__ Chi,
    unsigned short* __restrict__ Clo, const float* __restrict__ bias,
    int M, int N, int K, long long sA, long long sB, long long sC) {
  constexpr int BK = (SPLIT == 3) ? 32 : 64;
  constexpr int TILEB = 128 * BK * 2;
  constexpr int NT = (SPLIT == 3) ? 4 : 2;
  __shared__ __align__(16) unsigned char smem[2 * NT * TILEB];

  const int tid = threadIdx.x, lane = tid & 63, wid = tid >> 6;
  const int wm = wid >> 1, wn = wid & 1;
  const int r16 = lane & 15, q4 = lane >> 4;
  const int bn0 = blockIdx.x * 128, bm0 = blockIdx.y * 128;
  const int bz = blockIdx.z;

  Ah += (long long)bz * sA;
  Bh += (long long)bz * sB;
  if (SPLIT == 3) { Al += (long long)bz * sA; Bl += (long long)bz * sB; }
  const long long cb = (long long)bz * sC;

  auto stage = [&](int buf, int kt) {
    const int k0 = kt * BK;
    if (SPLIT == 3) {
      const unsigned short* src = (wid == 0) ? Ah : (wid == 1) ? Al : (wid == 2) ? Bh : Bl;
      const int row0 = (wid < 2) ? bm0 : bn0;
      unsigned char* dst = smem + (size_t)(buf * 4 + wid) * TILEB;
#pragma unroll
      for (int i = 0; i < 8; ++i) {
        const int row = i * 16 + (lane >> 2);
        const int sg = (lane & 3) ^ ((row >> 1) & 3);
        gload_lds16(src + (long long)(row0 + row) * K + k0 + sg * 8, dst + i * 1024);
      }
    } else {
      const unsigned short* src = (wid < 2) ? Ah : Bh;
      const int row0 = (wid < 2) ? bm0 : bn0;
      const int half = wid & 1;
      unsigned char* dst = smem + (size_t)(buf * 2 + (wid >> 1)) * TILEB + half * 8192;
#pragma unroll
      for (int i = 0; i < 8; ++i) {
        const int row = half * 64 + i * 8 + (lane >> 3);
        const int sg = (lane & 7) ^ (row & 7);
        gload_lds16(src + (long long)(row0 + row) * K + k0 + sg * 8, dst + i * 1024);
      }
    }
  };

  auto foff = [&](int r, int ks) -> int {
    return (BK == 64) ? (r * 128 + ((((ks << 2) + q4) ^ (r & 7)) << 4))
                      : (r * 64 + ((q4 ^ ((r >> 1) & 3)) << 4));
  };

  f32x4 acc[4][4];
#pragma unroll
  for (int mi = 0; mi < 4; ++mi)
#pragma unroll
    for (int ni = 0; ni < 4; ++ni) acc[mi][ni] = (f32x4){0.f, 0.f, 0.f, 0.f};

  const int nk = K / BK;
  int buf = 0;
  stage(0, 0);
  for (int kt = 0; kt < nk; ++kt) {
    __syncthreads();
    if (kt + 1 < nk) stage(buf ^ 1, kt + 1);
    const unsigned char* tA = smem + (size_t)((SPLIT == 3) ? (buf * 4 + 0) : (buf * 2 + 0)) * TILEB;
    const unsigned char* tB = smem + (size_t)((SPLIT == 3) ? (buf * 4 + 2) : (buf * 2 + 1)) * TILEB;
    const unsigned char* tAl = (SPLIT == 3) ? smem + (size_t)(buf * 4 + 1) * TILEB : nullptr;
    const unsigned char* tBl = (SPLIT == 3) ? smem + (size_t)(buf * 4 + 3) * TILEB : nullptr;
#pragma unroll
    for (int ks = 0; ks < BK / 32; ++ks) {
      bf16x8 a_h[4], b_h[4], a_l[4], b_l[4];
#pragma unroll
      for (int mi = 0; mi < 4; ++mi) {
        const int r = wm * 64 + mi * 16 + r16;
        const int off = foff(r, ks);
        a_h[mi] = *(const bf16x8*)(tA + off);
        if (SPLIT == 3) a_l[mi] = *(const bf16x8*)(tAl + off);
      }
#pragma unroll
      for (int ni = 0; ni < 4; ++ni) {
        const int r = wn * 64 + ni * 16 + r16;
        const int off = foff(r, ks);
        b_h[ni] = *(const bf16x8*)(tB + off);
        if (SPLIT == 3) b_l[ni] = *(const bf16x8*)(tBl + off);
      }
#pragma unroll
      for (int mi = 0; mi < 4; ++mi)
#pragma unroll
        for (int ni = 0; ni < 4; ++ni) {
          acc[mi][ni] = __builtin_amdgcn_mfma_f32_16x16x32_bf16(a_h[mi], b_h[ni], acc[mi][ni], 0, 0, 0);
          if (SPLIT == 3) {
            acc[mi][ni] = __builtin_amdgcn_mfma_f32_16x16x32_bf16(a_h[mi], b_l[ni], acc[mi][ni], 0, 0, 0);
            acc[mi][ni] = __builtin_amdgcn_mfma_f32_16x16x32_bf16(a_l[mi], b_h[ni], acc[mi][ni], 0, 0, 0);
          }
        }
    }
    buf ^= 1;
  }

#pragma unroll
  for (int mi = 0; mi < 4; ++mi) {
#pragma unroll
    for (int ni = 0; ni < 4; ++ni) {
      const int col = bn0 + wn * 64 + ni * 16 + r16;
      const float bv = BIAS ? bias[col] : 0.0f;
#pragma unroll
      for (int j = 0; j < 4; ++j) {
        const int row = bm0 + wm * 64 + mi * 16 + q4 * 4 + j;
        const float cv = acc[mi][ni][j] + bv;
        const long long idx = cb + (long long)row * N + col;
        if (OUTMODE == 0) {
          Cf[idx] = cv;
        } else if (OUTMODE == 1) {
          Chi[idx] = f2bf(cv);
        } else {
          unsigned short h = f2bf(cv);
          Chi[idx] = h;
          Clo[idx] = f2bf(cv - bf2f(h));
        }
      }
    }
  }
}

// ---------- host ----------
extern "C" void kernel_launch(void* const* d_in, const int* in_sizes, int n_in,
                              void* d_out, int out_size, void* d_ws, size_t ws_size,
                              hipStream_t stream) {
  const float* query = (const float*)d_in[0];
  const float* key   = (const float*)d_in[1];
  const float* value = (const float*)d_in[2];
  const float* cell  = (const float*)d_in[3];
  const float* seq   = (const float*)d_in[4];
  const float* W_k   = (const float*)d_in[5];
  const float* b_k   = (const float*)d_in[6];
  const float* W_o   = (const float*)d_in[7];
  const float* b_o   = (const float*)d_in[8];
  float* out = (float*)d_out;

  const int B = 8, S = 2048, D = 1024;
  const long long NE = (long long)B * S * D;
  const long long NS = (long long)B * S * S;

  unsigned char* ws = (unsigned char*)d_ws;
  size_t off = 0;
  auto alloc = [&](size_t bytes) -> unsigned char* {
    unsigned char* pp = ws + off;
    off += (bytes + 255) & ~(size_t)255;
    return pp;
  };
  unsigned short* qhi  = (unsigned short*)alloc(NE * 2);
  unsigned short* qlo  = (unsigned short*)alloc(NE * 2);
  unsigned short* kphi = (unsigned short*)alloc(NE * 2);
  unsigned short* kplo = (unsigned short*)alloc(NE * 2);
  unsigned short* vT   = (unsigned short*)alloc(NE * 2);
  unsigned short* khi  = (unsigned short*)alloc(NE * 2);  // becomes p after k_proj
  unsigned short* klo  = (unsigned short*)alloc(NE * 2);
  float*          scores = (float*)alloc(NS * 4);         // becomes xbf after softmax
  unsigned short* wkhi = (unsigned short*)alloc((size_t)D * D * 2);
  unsigned short* wklo = (unsigned short*)alloc((size_t)D * D * 2);
  unsigned short* wo   = (unsigned short*)alloc((size_t)D * D * 2);
  unsigned short* p    = khi;
  unsigned short* xbf  = (unsigned short*)scores;
  (void)ws_size; (void)in_sizes; (void)n_in; (void)out_size;

  // allow 128 KiB dynamic LDS on the 8-phase kernels (idempotent, host-only)
  (void)hipFuncSetAttribute(reinterpret_cast<const void*>(gemm256<3, 2, true>),
                            hipFuncAttributeMaxDynamicSharedMemorySize, 131072);
  (void)hipFuncSetAttribute(reinterpret_cast<const void*>(gemm256<3, 0, false>),
                            hipFuncAttributeMaxDynamicSharedMemorySize, 131072);

  // 1. hi/lo splits + casts
  split_kernel<<<dim3(NE / 1024), 256, 0, stream>>>(query, qhi, qlo, (int)(NE / 4));
  split_kernel<<<dim3(NE / 1024), 256, 0, stream>>>(key, khi, klo, (int)(NE / 4));
  split_kernel<<<dim3(D * D / 1024), 256, 0, stream>>>(W_k, wkhi, wklo, D * D / 4);
  cast_kernel<<<dim3(D * D / 1024), 256, 0, stream>>>(W_o, wo, D * D / 4);
  transpose_cast_kernel<<<dim3(S / 32, D / 32, B), dim3(32, 8), 0, stream>>>(value, vT, S, D);

  // 2. k_proj = key @ W_k^T + b_k  (8-phase 256², split precision, split output)
  gemm256<3, 2, true><<<dim3(D / 256, (B * S) / 256, 1), 512, 131072, stream>>>(
      khi, klo, wkhi, wklo, nullptr, kphi, kplo, b_k, B * S, D, D, 0, 0, 0);

  // 3. scores = q @ k_proj^T  (8-phase 256², batched, split precision, fp32 out)
  gemm256<3, 0, false><<<dim3(S / 256, S / 256, B), 512, 131072, stream>>>(
      qhi, qlo, kphi, kplo, scores, nullptr, nullptr, nullptr, S, S, D,
      (long long)S * D, (long long)S * D, (long long)S * S);

  // 4. masked softmax -> p (bf16)
  softmax_kernel<<<dim3(B * S), 256, 0, stream>>>(scores, cell, seq, p, S);

  // 5. x = p @ vT^T  (batched, bf16 out)
  gemm_bt<1, 1, false><<<dim3(D / 128, S / 128, B), 256, 0, stream>>>(
      p, nullptr, vT, nullptr, nullptr, xbf, nullptr, nullptr, S, D, S,
      (long long)S * S, (long long)S * D, (long long)S * D);

  // 6. out = x @ W_o^T + b_o  (fp32 out)
  gemm_bt<1, 0, true><<<dim3(D / 128, (B * S) / 128, 1), 256, 0, stream>>>(
      xbf, nullptr, wo, nullptr, out, nullptr, nullptr, b_o, B * S, D, D, 0, 0, 0);
}